// Round 3
// baseline (1375.842 us; speedup 1.0000x reference)
//
#include <hip/hip_runtime.h>

#define NE 8
#define NTOK 4096
#define CD 1024
#define FD 3584
#define NPAIR 8192
#define NPAD 8320   // NPAIR + 128 row pad for tile overrun

typedef __attribute__((ext_vector_type(8))) short bf16x8;
typedef __attribute__((ext_vector_type(4))) float f32x4;
typedef __attribute__((ext_vector_type(8))) unsigned short u16x8;
typedef unsigned int u32;

__device__ __forceinline__ unsigned short f2bf(float f) {
  union { float f; unsigned u; } v; v.f = f;
  unsigned r = v.u + 0x7fffu + ((v.u >> 16) & 1u);
  return (unsigned short)(r >> 16);
}

// async global->LDS, 16B per lane; lds base must be wave-uniform (HW: base + lane*16)
__device__ __forceinline__ void gld16(unsigned short* lds, const unsigned short* g) {
  __builtin_amdgcn_global_load_lds(
      (const __attribute__((address_space(1))) u32*)g,
      (__attribute__((address_space(3))) u32*)lds, 16, 0, 0);
}

#define MFMA16(a, b, c) __builtin_amdgcn_mfma_f32_16x16x32_bf16((a), (b), (c), 0, 0, 0)

// ---------------- router: logits, softmax, top-2, gates, aux partials ----------------
__global__ __launch_bounds__(256) void router_kernel(
    const float* __restrict__ x, const float* __restrict__ rw,
    unsigned* __restrict__ counts, float* __restrict__ p_sum,
    unsigned* __restrict__ t2e, float* __restrict__ t2g) {
  int wave = threadIdx.x >> 6, lane = threadIdx.x & 63;
  int t = blockIdx.x * 4 + wave;
  if (t >= NTOK) return;
  const float4* xv = (const float4*)(x + (size_t)t * CD) + lane * 4;
  float4 x0 = xv[0], x1 = xv[1], x2 = xv[2], x3 = xv[3];
  float lg[NE];
#pragma unroll
  for (int e = 0; e < NE; ++e) {
    const float4* wv = (const float4*)(rw + (size_t)e * CD) + lane * 4;
    float4 w0 = wv[0], w1v = wv[1], w2v = wv[2], w3v = wv[3];
    float s;
    s  = x0.x*w0.x + x0.y*w0.y + x0.z*w0.z + x0.w*w0.w;
    s += x1.x*w1v.x + x1.y*w1v.y + x1.z*w1v.z + x1.w*w1v.w;
    s += x2.x*w2v.x + x2.y*w2v.y + x2.z*w2v.z + x2.w*w2v.w;
    s += x3.x*w3v.x + x3.y*w3v.y + x3.z*w3v.z + x3.w*w3v.w;
    lg[e] = s;
  }
#pragma unroll
  for (int e = 0; e < NE; ++e)
#pragma unroll
    for (int off = 32; off; off >>= 1) lg[e] += __shfl_xor(lg[e], off);
  if (lane == 0) {
    float m = lg[0];
#pragma unroll
    for (int e = 1; e < NE; ++e) m = fmaxf(m, lg[e]);
    float p[NE], s = 0.f;
#pragma unroll
    for (int e = 0; e < NE; ++e) { p[e] = expf(lg[e] - m); s += p[e]; }
    float inv = 1.f / s;
    int i1 = 0; float b1 = p[0];
#pragma unroll
    for (int e = 1; e < NE; ++e) if (p[e] > b1) { b1 = p[e]; i1 = e; }
    int i2 = -1; float b2 = -1.f;
#pragma unroll
    for (int e = 0; e < NE; ++e) if (e != i1 && p[e] > b2) { b2 = p[e]; i2 = e; }
    float gs = 1.f / (b1 + b2);   // exp-scale cancels: probs[i1]/(probs[i1]+probs[i2])
    t2e[2*t]   = (unsigned)i1; t2g[2*t]   = b1 * gs;
    t2e[2*t+1] = (unsigned)i2; t2g[2*t+1] = b2 * gs;
    atomicAdd(&counts[i1], 1u);
    atomicAdd(&counts[i2], 1u);
#pragma unroll
    for (int e = 0; e < NE; ++e) atomicAdd(&p_sum[e], p[e] * inv);
  }
}

// ---------------- scan: offsets + aux loss ----------------
__global__ void scan_kernel(const unsigned* __restrict__ counts, const float* __restrict__ p_sum,
                            unsigned* __restrict__ offsets, float* __restrict__ aux_out) {
  if (threadIdx.x == 0 && blockIdx.x == 0) {
    unsigned off = 0; float aux = 0.f;
    for (int e = 0; e < NE; ++e) {
      offsets[e] = off; off += counts[e];
      aux += ((float)counts[e] / (float)NPAIR) * (p_sum[e] / (float)NTOK);
    }
    *aux_out = (float)NE * aux;
  }
}

// ---------------- build: compact per-expert token lists + gather x -> bf16 ----------------
__global__ __launch_bounds__(256) void build_kernel(
    const float* __restrict__ x, const unsigned* __restrict__ t2e, const float* __restrict__ t2g,
    const unsigned* __restrict__ offsets, unsigned* __restrict__ cursors,
    unsigned* __restrict__ gtok, float* __restrict__ ggate, unsigned short* __restrict__ xg) {
  int wave = threadIdx.x >> 6, lane = threadIdx.x & 63;
  int pair = blockIdx.x * 4 + wave;
  if (pair >= NPAIR) return;
  int t = pair >> 1;
  unsigned e = t2e[pair];
  unsigned pos = 0;
  if (lane == 0) pos = atomicAdd(&cursors[e], 1u);
  pos = (unsigned)__shfl((int)pos, 0);
  unsigned g = offsets[e] + pos;
  if (lane == 0) { gtok[g] = (unsigned)t; ggate[g] = t2g[pair]; }
  const float4* xv = (const float4*)(x + (size_t)t * CD) + lane * 4;
  float4 a = xv[0], b = xv[1], c = xv[2], d = xv[3];
  u16x8* dst = (u16x8*)(xg + (size_t)g * CD + lane * 16);
  dst[0] = u16x8{f2bf(a.x), f2bf(a.y), f2bf(a.z), f2bf(a.w), f2bf(b.x), f2bf(b.y), f2bf(b.z), f2bf(b.w)};
  dst[1] = u16x8{f2bf(c.x), f2bf(c.y), f2bf(c.z), f2bf(c.w), f2bf(d.x), f2bf(d.y), f2bf(d.z), f2bf(d.w)};
}

// ---------------- fused weight fp32 -> bf16 convert (3 segments, 1 launch) ----------------
__global__ __launch_bounds__(256) void convert3_kernel(
    const float4* __restrict__ s1, u16x8* __restrict__ d1,
    const float4* __restrict__ s2, u16x8* __restrict__ d2,
    const float4* __restrict__ s3, u16x8* __restrict__ d3, int n8each) {
  int G = gridDim.x / 3;
  int seg = blockIdx.x / G;
  int bid = blockIdx.x - seg * G;
  const float4* src = seg == 0 ? s1 : (seg == 1 ? s2 : s3);
  u16x8*       dst = seg == 0 ? d1 : (seg == 1 ? d2 : d3);
  int i = bid * 256 + threadIdx.x;
  int stride = G * 256;
  for (; i < n8each; i += stride) {
    float4 a = src[2*i], b = src[2*i+1];
    dst[i] = u16x8{f2bf(a.x), f2bf(a.y), f2bf(a.z), f2bf(a.w), f2bf(b.x), f2bf(b.y), f2bf(b.z), f2bf(b.w)};
  }
}

// ---------------- GEMM1: h = (x@w1^T) * silu(x@w2^T), grouped by expert ----------------
// m97 structure: 128x128 tile, BK=64, linear LDS, global_load_lds(16B), 2 barriers/K-step.
// grid: e(8) x rb(32) x cb(28); block 512 = 8 waves (2x4), wave tile 64x32, dual acc
template<bool WB>
__global__ __launch_bounds__(512) void gemm1_kernel(
    const unsigned short* __restrict__ xg, const void* __restrict__ w1p, const void* __restrict__ w2p,
    unsigned short* __restrict__ h, const unsigned* __restrict__ offsets, const unsigned* __restrict__ counts) {
  int bx = blockIdx.x;
  int e = bx / (32 * 28); int rem = bx - e * 32 * 28;
  int rb = rem / 28, cb = rem % 28;
  int cnt = (int)counts[e];
  if (rb * 128 >= cnt) return;
  int base = (int)offsets[e];

  __shared__ unsigned short As[128 * 64];   // 16 KB, linear: row*64 + col
  __shared__ unsigned short B1s[128 * 64];
  __shared__ unsigned short B2s[128 * 64];

  int tid = threadIdx.x, wave = tid >> 6, lane = tid & 63;
  int wm = wave >> 2, wn = wave & 3;          // 2 x 4 wave grid
  int qr = lane >> 3;                         // row within 8-row chunk
  int qc = (lane & 7) * 8;                    // col elems within chunk row
  int sr = tid >> 3;                          // lean staging row 0..63
  int sc = (tid & 7) * 8;

  f32x4 acc1[4][2] = {};
  f32x4 acc2[4][2] = {};

  const unsigned short* a_src = xg + (size_t)(base + rb * 128) * CD;
  size_t wofs = ((size_t)e * FD + cb * 128) * CD;
  const unsigned short* b1_bf = (const unsigned short*)w1p + wofs;
  const unsigned short* b2_bf = (const unsigned short*)w2p + wofs;
  const float* b1_f = (const float*)w1p + wofs;
  const float* b2_f = (const float*)w2p + wofs;

  for (int kt = 0; kt < CD / 64; ++kt) {
    int k0 = kt * 64;
    __syncthreads();                           // previous compute done; safe to overwrite LDS
    if (WB) {
      // 16 chunks/tile (8 rows x 64 cols = 1 KiB each); wave w stages chunks w, w+8
#pragma unroll
      for (int it = 0; it < 2; ++it) {
        int q = wave + it * 8;
        int row = q * 8 + qr;
        gld16(&As[q * 512],  a_src + (size_t)row * CD + k0 + qc);
        gld16(&B1s[q * 512], b1_bf + (size_t)row * CD + k0 + qc);
        gld16(&B2s[q * 512], b2_bf + (size_t)row * CD + k0 + qc);
      }
    } else {
#pragma unroll
      for (int it = 0; it < 2; ++it) {
        int r = sr + it * 64;
        *(u16x8*)&As[r * 64 + sc] = *(const u16x8*)(a_src + (size_t)r * CD + k0 + sc);
        const float4* s1 = (const float4*)(b1_f + (size_t)r * CD + k0 + sc);
        float4 fa = s1[0], fb = s1[1];
        *(u16x8*)&B1s[r * 64 + sc] = u16x8{f2bf(fa.x), f2bf(fa.y), f2bf(fa.z), f2bf(fa.w),
                                           f2bf(fb.x), f2bf(fb.y), f2bf(fb.z), f2bf(fb.w)};
        const float4* s2 = (const float4*)(b2_f + (size_t)r * CD + k0 + sc);
        float4 ga = s2[0], gb = s2[1];
        *(u16x8*)&B2s[r * 64 + sc] = u16x8{f2bf(ga.x), f2bf(ga.y), f2bf(ga.z), f2bf(ga.w),
                                           f2bf(gb.x), f2bf(gb.y), f2bf(gb.z), f2bf(gb.w)};
      }
    }
    __syncthreads();                           // drains vmcnt (async LDS writes) + lgkm
#pragma unroll
    for (int kk = 0; kk < 2; ++kk) {
      int ko = kk * 32 + (lane >> 4) * 8;
      bf16x8 af[4];
#pragma unroll
      for (int mi = 0; mi < 4; ++mi)
        af[mi] = *(const bf16x8*)&As[(wm * 64 + mi * 16 + (lane & 15)) * 64 + ko];
#pragma unroll
      for (int ni = 0; ni < 2; ++ni) {
        int brow = wn * 32 + ni * 16 + (lane & 15);
        bf16x8 b1 = *(const bf16x8*)&B1s[brow * 64 + ko];
        bf16x8 b2 = *(const bf16x8*)&B2s[brow * 64 + ko];
#pragma unroll
        for (int mi = 0; mi < 4; ++mi) {
          acc1[mi][ni] = MFMA16(af[mi], b1, acc1[mi][ni]);
          acc2[mi][ni] = MFMA16(af[mi], b2, acc2[mi][ni]);
        }
      }
    }
  }
  // epilogue: h = (x.w1) * silu(x.w2)
#pragma unroll
  for (int mi = 0; mi < 4; ++mi) {
#pragma unroll
    for (int ni = 0; ni < 2; ++ni) {
      int c = cb * 128 + wn * 32 + ni * 16 + (lane & 15);
#pragma unroll
      for (int r4 = 0; r4 < 4; ++r4) {
        int r = rb * 128 + wm * 64 + mi * 16 + (lane >> 4) * 4 + r4;
        if (r < cnt) {
          float z = acc2[mi][ni][r4];
          float sig = 1.f / (1.f + expf(-z));
          float v = acc1[mi][ni][r4] * (z * sig);
          h[(size_t)(base + r) * FD + c] = f2bf(v);
        }
      }
    }
  }
}

// ---------------- GEMM2: y[tok] += gate * (h @ w3^T), grouped by expert ----------------
// grid: e(8) x rb(32) x cb(8); block 512 = 8 waves (2x4)
template<bool WB>
__global__ __launch_bounds__(512) void gemm2_kernel(
    const unsigned short* __restrict__ h, const void* __restrict__ w3p, float* __restrict__ y,
    const unsigned* __restrict__ offsets, const unsigned* __restrict__ counts,
    const unsigned* __restrict__ gtok, const float* __restrict__ ggate) {
  int bx = blockIdx.x;
  int e = bx / (32 * 8); int rem = bx - e * 32 * 8;
  int rb = rem / 8, cb = rem % 8;
  int cnt = (int)counts[e];
  if (rb * 128 >= cnt) return;
  int base = (int)offsets[e];

  __shared__ unsigned short As[128 * 64];
  __shared__ unsigned short Bs[128 * 64];

  int tid = threadIdx.x, wave = tid >> 6, lane = tid & 63;
  int wm = wave >> 2, wn = wave & 3;
  int qr = lane >> 3;
  int qc = (lane & 7) * 8;
  int sr = tid >> 3;
  int sc = (tid & 7) * 8;

  f32x4 acc[4][2] = {};

  const unsigned short* a_src = h + (size_t)(base + rb * 128) * FD;
  size_t wofs = ((size_t)e * CD + cb * 128) * FD;
  const unsigned short* b_bf = (const unsigned short*)w3p + wofs;
  const float* b_f = (const float*)w3p + wofs;

  for (int kt = 0; kt < FD / 64; ++kt) {
    int k0 = kt * 64;
    __syncthreads();
    if (WB) {
#pragma unroll
      for (int it = 0; it < 2; ++it) {
        int q = wave + it * 8;
        int row = q * 8 + qr;
        gld16(&As[q * 512], a_src + (size_t)row * FD + k0 + qc);
        gld16(&Bs[q * 512], b_bf  + (size_t)row * FD + k0 + qc);
      }
    } else {
#pragma unroll
      for (int it = 0; it < 2; ++it) {
        int r = sr + it * 64;
        *(u16x8*)&As[r * 64 + sc] = *(const u16x8*)(a_src + (size_t)r * FD + k0 + sc);
        const float4* s1 = (const float4*)(b_f + (size_t)r * FD + k0 + sc);
        float4 fa = s1[0], fb = s1[1];
        *(u16x8*)&Bs[r * 64 + sc] = u16x8{f2bf(fa.x), f2bf(fa.y), f2bf(fa.z), f2bf(fa.w),
                                          f2bf(fb.x), f2bf(fb.y), f2bf(fb.z), f2bf(fb.w)};
      }
    }
    __syncthreads();
#pragma unroll
    for (int kk = 0; kk < 2; ++kk) {
      int ko = kk * 32 + (lane >> 4) * 8;
      bf16x8 af[4];
#pragma unroll
      for (int mi = 0; mi < 4; ++mi)
        af[mi] = *(const bf16x8*)&As[(wm * 64 + mi * 16 + (lane & 15)) * 64 + ko];
#pragma unroll
      for (int ni = 0; ni < 2; ++ni) {
        int brow = wn * 32 + ni * 16 + (lane & 15);
        bf16x8 bfr = *(const bf16x8*)&Bs[brow * 64 + ko];
#pragma unroll
        for (int mi = 0; mi < 4; ++mi)
          acc[mi][ni] = MFMA16(af[mi], bfr, acc[mi][ni]);
      }
    }
  }
  // epilogue: gated scatter-add into y (exactly 2 contributions per output element)
#pragma unroll
  for (int mi = 0; mi < 4; ++mi) {
#pragma unroll
    for (int r4 = 0; r4 < 4; ++r4) {
      int rloc = rb * 128 + wm * 64 + mi * 16 + (lane >> 4) * 4 + r4;
      if (rloc < cnt) {
        unsigned t = gtok[base + rloc];
        float g = ggate[base + rloc];
#pragma unroll
        for (int ni = 0; ni < 2; ++ni) {
          int c = cb * 128 + wn * 32 + ni * 16 + (lane & 15);
          atomicAdd(&y[(size_t)t * CD + c], g * acc[mi][ni][r4]);
        }
      }
    }
  }
}

// ---------------- launch ----------------
extern "C" void kernel_launch(void* const* d_in, const int* in_sizes, int n_in,
                              void* d_out, int out_size, void* d_ws, size_t ws_size,
                              hipStream_t stream) {
  const float* x  = (const float*)d_in[0];
  const float* rw = (const float*)d_in[1];
  const float* w1 = (const float*)d_in[2];
  const float* w2 = (const float*)d_in[3];
  const float* w3 = (const float*)d_in[4];
  float* y = (float*)d_out;

  char* ws = (char*)d_ws;
  unsigned* counts  = (unsigned*)(ws + 0);
  unsigned* cursors = (unsigned*)(ws + 32);
  float*    p_sum   = (float*)(ws + 64);
  unsigned* offsets = (unsigned*)(ws + 96);
  unsigned* t2e     = (unsigned*)(ws + 256);
  float*    t2g     = (float*)(ws + 256 + 4 * NPAIR);
  unsigned* gtok    = (unsigned*)(ws + 256 + 8 * NPAIR);
  float*    ggate   = (float*)(ws + 256 + 8 * NPAIR + 4 * NPAD);
  size_t o = 256 + 8 * (size_t)NPAIR + 8 * (size_t)NPAD;
  o = (o + 511) & ~(size_t)511;
  unsigned short* xg = (unsigned short*)(ws + o);           o += (size_t)NPAD * CD * 2;
  unsigned short* hb = (unsigned short*)(ws + o);           o += (size_t)NPAD * FD * 2;
  unsigned short* w1b = (unsigned short*)(ws + o);          o += (size_t)NE * FD * CD * 2;
  unsigned short* w2b = (unsigned short*)(ws + o);          o += (size_t)NE * FD * CD * 2;
  unsigned short* w3b = (unsigned short*)(ws + o);          o += (size_t)NE * CD * FD * 2;
  size_t full_need = o;
  bool full = ws_size >= full_need;

  hipMemsetAsync(d_out, 0, (size_t)NTOK * CD * sizeof(float), stream);
  hipMemsetAsync(ws, 0, 96, stream);

  router_kernel<<<NTOK / 4, 256, 0, stream>>>(x, rw, counts, p_sum, t2e, t2g);
  scan_kernel<<<1, 64, 0, stream>>>(counts, p_sum, offsets, y + (size_t)NTOK * CD);
  build_kernel<<<NPAIR / 4, 256, 0, stream>>>(x, t2e, t2g, offsets, cursors, gtok, ggate, xg);

  if (full) {
    int n8 = NE * FD * CD / 8;
    convert3_kernel<<<3 * 2048, 256, 0, stream>>>((const float4*)w1, (u16x8*)w1b,
                                                  (const float4*)w2, (u16x8*)w2b,
                                                  (const float4*)w3, (u16x8*)w3b, n8);
    gemm1_kernel<true><<<NE * 32 * 28, 512, 0, stream>>>(xg, w1b, w2b, hb, offsets, counts);
    gemm2_kernel<true><<<NE * 32 * 8, 512, 0, stream>>>(hb, w3b, y, offsets, counts, gtok, ggate);
  } else {
    gemm1_kernel<false><<<NE * 32 * 28, 512, 0, stream>>>(xg, w1, w2, hb, offsets, counts);
    gemm2_kernel<false><<<NE * 32 * 8, 512, 0, stream>>>(hb, w3, y, offsets, counts, gtok, ggate);
  }
}

// Round 5
// 879.155 us; speedup vs baseline: 1.5650x; 1.5650x over previous
//
#include <hip/hip_runtime.h>

#define NE 8
#define NTOK 4096
#define CD 1024
#define FD 3584
#define NPAIR 8192
#define NPAD 8320   // NPAIR + 128 row pad for tile overrun
#define RBLK 256    // router blocks
#define RTOK 16     // tokens per router block

typedef __attribute__((ext_vector_type(8))) short bf16x8;
typedef __attribute__((ext_vector_type(4))) float f32x4;
typedef __attribute__((ext_vector_type(8))) unsigned short u16x8;
typedef unsigned int u32;

__device__ __forceinline__ unsigned short f2bf(float f) {
  union { float f; unsigned u; } v; v.f = f;
  unsigned r = v.u + 0x7fffu + ((v.u >> 16) & 1u);
  return (unsigned short)(r >> 16);
}

// async global->LDS, 16B per lane; lds base must be wave-uniform (HW: base + lane*16)
__device__ __forceinline__ void gld16(unsigned short* lds, const unsigned short* g) {
  __builtin_amdgcn_global_load_lds(
      (const __attribute__((address_space(1))) u32*)g,
      (__attribute__((address_space(3))) u32*)lds, 16, 0, 0);
}

#define MFMA16(a, b, c) __builtin_amdgcn_mfma_f32_16x16x32_bf16((a), (b), (c), 0, 0, 0)

// ---------------- router: logits, softmax, top-2, gates; block-partial counts/p_sum ----------------
// No global same-address atomics (the 480us lesson): LDS accumulate, write per-block partials.
__global__ __launch_bounds__(256) void router_kernel(
    const float* __restrict__ x, const float* __restrict__ rw,
    unsigned* __restrict__ pcnt, float* __restrict__ ppsum,
    unsigned* __restrict__ t2e, float* __restrict__ t2g) {
  __shared__ unsigned s_cnt[NE];
  __shared__ float s_ps[NE];
  if (threadIdx.x < NE) { s_cnt[threadIdx.x] = 0u; s_ps[threadIdx.x] = 0.f; }
  __syncthreads();
  int wave = threadIdx.x >> 6, lane = threadIdx.x & 63;
  // hoist router weights: lane-contiguous float4 chunks (coalesced)
  float4 w[NE][4];
#pragma unroll
  for (int e = 0; e < NE; ++e) {
    const float4* wr = (const float4*)(rw + (size_t)e * CD);
    w[e][0] = wr[2*lane]; w[e][1] = wr[2*lane+1];
    w[e][2] = wr[128+2*lane]; w[e][3] = wr[129+2*lane];
  }
  for (int it = 0; it < RTOK / 4; ++it) {
    int t = blockIdx.x * RTOK + it * 4 + wave;
    const float4* xr = (const float4*)(x + (size_t)t * CD);
    float4 a0 = xr[2*lane], a1 = xr[2*lane+1], a2 = xr[128+2*lane], a3 = xr[129+2*lane];
    float lg[NE];
#pragma unroll
    for (int e = 0; e < NE; ++e) {
      float s;
      s  = a0.x*w[e][0].x + a0.y*w[e][0].y + a0.z*w[e][0].z + a0.w*w[e][0].w;
      s += a1.x*w[e][1].x + a1.y*w[e][1].y + a1.z*w[e][1].z + a1.w*w[e][1].w;
      s += a2.x*w[e][2].x + a2.y*w[e][2].y + a2.z*w[e][2].z + a2.w*w[e][2].w;
      s += a3.x*w[e][3].x + a3.y*w[e][3].y + a3.z*w[e][3].z + a3.w*w[e][3].w;
      lg[e] = s;
    }
#pragma unroll
    for (int e = 0; e < NE; ++e)
#pragma unroll
      for (int off = 32; off; off >>= 1) lg[e] += __shfl_xor(lg[e], off);
    if (lane == 0) {
      float m = lg[0];
#pragma unroll
      for (int e = 1; e < NE; ++e) m = fmaxf(m, lg[e]);
      float p[NE], s = 0.f;
#pragma unroll
      for (int e = 0; e < NE; ++e) { p[e] = expf(lg[e] - m); s += p[e]; }
      float inv = 1.f / s;
      int i1 = 0; float b1 = p[0];
#pragma unroll
      for (int e = 1; e < NE; ++e) if (p[e] > b1) { b1 = p[e]; i1 = e; }
      int i2 = -1; float b2 = -1.f;
#pragma unroll
      for (int e = 0; e < NE; ++e) if (e != i1 && p[e] > b2) { b2 = p[e]; i2 = e; }
      float gs = 1.f / (b1 + b2);   // exp-scale cancels: probs[i1]/(probs[i1]+probs[i2])
      t2e[2*t]   = (unsigned)i1; t2g[2*t]   = b1 * gs;
      t2e[2*t+1] = (unsigned)i2; t2g[2*t+1] = b2 * gs;
      atomicAdd(&s_cnt[i1], 1u);          // LDS atomics: cheap
      atomicAdd(&s_cnt[i2], 1u);
#pragma unroll
      for (int e = 0; e < NE; ++e) atomicAdd(&s_ps[e], p[e] * inv);
    }
  }
  __syncthreads();
  if (threadIdx.x < NE) {
    pcnt[blockIdx.x * NE + threadIdx.x]  = s_cnt[threadIdx.x];
    ppsum[blockIdx.x * NE + threadIdx.x] = s_ps[threadIdx.x];
  }
}

// ---------------- scan: reduce partials -> counts, offsets, aux ----------------
__global__ void scan_kernel(const unsigned* __restrict__ pcnt, const float* __restrict__ ppsum,
                            unsigned* __restrict__ counts, unsigned* __restrict__ offsets,
                            float* __restrict__ aux_out) {
  int lane = threadIdx.x & 63;
  int e = lane >> 3, c = lane & 7;
  unsigned cs = 0; float ps = 0.f;
  for (int b = c; b < RBLK; b += 8) { cs += pcnt[b * NE + e]; ps += ppsum[b * NE + e]; }
#pragma unroll
  for (int off = 1; off < 8; off <<= 1) {
    cs += __shfl_xor(cs, off);
    ps += __shfl_xor(ps, off);
  }
  __shared__ unsigned tc[NE];
  __shared__ float tp[NE];
  if (c == 0) { tc[e] = cs; tp[e] = ps; }
  __syncthreads();
  if (threadIdx.x == 0) {
    unsigned off = 0; float aux = 0.f;
    for (int i = 0; i < NE; ++i) {
      counts[i] = tc[i]; offsets[i] = off; off += tc[i];
      aux += ((float)tc[i] / (float)NPAIR) * (tp[i] / (float)NTOK);
    }
    *aux_out = (float)NE * aux;
  }
}

// ---------------- build: block-ranked compaction, 8 cursor atomics per block ----------------
__global__ __launch_bounds__(256) void build_kernel(
    const unsigned* __restrict__ t2e, const float* __restrict__ t2g,
    const unsigned* __restrict__ offsets, unsigned* __restrict__ cursors,
    unsigned* __restrict__ gtok, float* __restrict__ ggate) {
  __shared__ unsigned cnt_l[NE], base_l[NE];
  if (threadIdx.x < NE) cnt_l[threadIdx.x] = 0u;
  __syncthreads();
  int p = blockIdx.x * 256 + threadIdx.x;
  unsigned e = t2e[p];
  unsigned r = atomicAdd(&cnt_l[e], 1u);
  __syncthreads();
  if (threadIdx.x < NE)
    base_l[threadIdx.x] = offsets[threadIdx.x] + atomicAdd(&cursors[threadIdx.x], cnt_l[threadIdx.x]);
  __syncthreads();
  unsigned g = base_l[e] + r;
  gtok[g] = (unsigned)(p >> 1);
  ggate[g] = t2g[p];
}

// ---------------- gather: x[token] -> xg[group row] (fp32 -> bf16, coalesced) ----------------
__global__ __launch_bounds__(256) void gather_kernel(
    const float* __restrict__ x, const unsigned* __restrict__ gtok,
    unsigned short* __restrict__ xg) {
  int wave = threadIdx.x >> 6, lane = threadIdx.x & 63;
  int g = blockIdx.x * 4 + wave;
  unsigned t = gtok[g];
  const float4* xr = (const float4*)(x + (size_t)t * CD);
  unsigned short* dst = xg + (size_t)g * CD;
#pragma unroll
  for (int j = 0; j < 2; ++j) {
    float4 a = xr[j*128 + 2*lane], b = xr[j*128 + 2*lane + 1];
    *(u16x8*)(dst + j*512 + lane*8) =
        u16x8{f2bf(a.x), f2bf(a.y), f2bf(a.z), f2bf(a.w), f2bf(b.x), f2bf(b.y), f2bf(b.z), f2bf(b.w)};
  }
}

// ---------------- fused weight fp32 -> bf16 convert (3 segments, 1 launch) ----------------
__global__ __launch_bounds__(256) void convert3_kernel(
    const float4* __restrict__ s1, u16x8* __restrict__ d1,
    const float4* __restrict__ s2, u16x8* __restrict__ d2,
    const float4* __restrict__ s3, u16x8* __restrict__ d3, int n8each) {
  int G = gridDim.x / 3;
  int seg = blockIdx.x / G;
  int bid = blockIdx.x - seg * G;
  const float4* src = seg == 0 ? s1 : (seg == 1 ? s2 : s3);
  u16x8*       dst = seg == 0 ? d1 : (seg == 1 ? d2 : d3);
  int i = bid * 256 + threadIdx.x;
  int stride = G * 256;
  for (; i < n8each; i += stride) {
    float4 a = src[2*i], b = src[2*i+1];
    dst[i] = u16x8{f2bf(a.x), f2bf(a.y), f2bf(a.z), f2bf(a.w), f2bf(b.x), f2bf(b.y), f2bf(b.z), f2bf(b.w)};
  }
}

// ---------------- GEMM1: h = (x@w1^T) * silu(x@w2^T), grouped by expert ----------------
// m97 structure: 128x128 tile, BK=64, linear LDS, global_load_lds(16B), 2 barriers/K-step.
template<bool WB>
__global__ __launch_bounds__(512) void gemm1_kernel(
    const unsigned short* __restrict__ xg, const void* __restrict__ w1p, const void* __restrict__ w2p,
    unsigned short* __restrict__ h, const unsigned* __restrict__ offsets, const unsigned* __restrict__ counts) {
  int bx = blockIdx.x;
  int e = bx / (32 * 28); int rem = bx - e * 32 * 28;
  int rb = rem / 28, cb = rem % 28;
  int cnt = (int)counts[e];
  if (rb * 128 >= cnt) return;
  int base = (int)offsets[e];

  __shared__ unsigned short As[128 * 64];   // 16 KB, linear: row*64 + col
  __shared__ unsigned short B1s[128 * 64];
  __shared__ unsigned short B2s[128 * 64];

  int tid = threadIdx.x, wave = tid >> 6, lane = tid & 63;
  int wm = wave >> 2, wn = wave & 3;          // 2 x 4 wave grid
  int qr = lane >> 3;                         // row within 8-row chunk
  int qc = (lane & 7) * 8;                    // col elems within chunk row
  int sr = tid >> 3;                          // lean staging row 0..63
  int sc = (tid & 7) * 8;

  f32x4 acc1[4][2] = {};
  f32x4 acc2[4][2] = {};

  const unsigned short* a_src = xg + (size_t)(base + rb * 128) * CD;
  size_t wofs = ((size_t)e * FD + cb * 128) * CD;
  const unsigned short* b1_bf = (const unsigned short*)w1p + wofs;
  const unsigned short* b2_bf = (const unsigned short*)w2p + wofs;
  const float* b1_f = (const float*)w1p + wofs;
  const float* b2_f = (const float*)w2p + wofs;

  for (int kt = 0; kt < CD / 64; ++kt) {
    int k0 = kt * 64;
    __syncthreads();
    if (WB) {
#pragma unroll
      for (int it = 0; it < 2; ++it) {
        int q = wave + it * 8;
        int row = q * 8 + qr;
        gld16(&As[q * 512],  a_src + (size_t)row * CD + k0 + qc);
        gld16(&B1s[q * 512], b1_bf + (size_t)row * CD + k0 + qc);
        gld16(&B2s[q * 512], b2_bf + (size_t)row * CD + k0 + qc);
      }
    } else {
#pragma unroll
      for (int it = 0; it < 2; ++it) {
        int r = sr + it * 64;
        *(u16x8*)&As[r * 64 + sc] = *(const u16x8*)(a_src + (size_t)r * CD + k0 + sc);
        const float4* s1 = (const float4*)(b1_f + (size_t)r * CD + k0 + sc);
        float4 fa = s1[0], fb = s1[1];
        *(u16x8*)&B1s[r * 64 + sc] = u16x8{f2bf(fa.x), f2bf(fa.y), f2bf(fa.z), f2bf(fa.w),
                                           f2bf(fb.x), f2bf(fb.y), f2bf(fb.z), f2bf(fb.w)};
        const float4* s2 = (const float4*)(b2_f + (size_t)r * CD + k0 + sc);
        float4 ga = s2[0], gb = s2[1];
        *(u16x8*)&B2s[r * 64 + sc] = u16x8{f2bf(ga.x), f2bf(ga.y), f2bf(ga.z), f2bf(ga.w),
                                           f2bf(gb.x), f2bf(gb.y), f2bf(gb.z), f2bf(gb.w)};
      }
    }
    __syncthreads();
#pragma unroll
    for (int kk = 0; kk < 2; ++kk) {
      int ko = kk * 32 + (lane >> 4) * 8;
      bf16x8 af[4];
#pragma unroll
      for (int mi = 0; mi < 4; ++mi)
        af[mi] = *(const bf16x8*)&As[(wm * 64 + mi * 16 + (lane & 15)) * 64 + ko];
#pragma unroll
      for (int ni = 0; ni < 2; ++ni) {
        int brow = wn * 32 + ni * 16 + (lane & 15);
        bf16x8 b1 = *(const bf16x8*)&B1s[brow * 64 + ko];
        bf16x8 b2 = *(const bf16x8*)&B2s[brow * 64 + ko];
#pragma unroll
        for (int mi = 0; mi < 4; ++mi) {
          acc1[mi][ni] = MFMA16(af[mi], b1, acc1[mi][ni]);
          acc2[mi][ni] = MFMA16(af[mi], b2, acc2[mi][ni]);
        }
      }
    }
  }
#pragma unroll
  for (int mi = 0; mi < 4; ++mi) {
#pragma unroll
    for (int ni = 0; ni < 2; ++ni) {
      int c = cb * 128 + wn * 32 + ni * 16 + (lane & 15);
#pragma unroll
      for (int r4 = 0; r4 < 4; ++r4) {
        int r = rb * 128 + wm * 64 + mi * 16 + (lane >> 4) * 4 + r4;
        if (r < cnt) {
          float z = acc2[mi][ni][r4];
          float sig = 1.f / (1.f + expf(-z));
          float v = acc1[mi][ni][r4] * (z * sig);
          h[(size_t)(base + r) * FD + c] = f2bf(v);
        }
      }
    }
  }
}

// ---------------- GEMM2: y[tok] += gate * (h @ w3^T), grouped by expert ----------------
template<bool WB>
__global__ __launch_bounds__(512) void gemm2_kernel(
    const unsigned short* __restrict__ h, const void* __restrict__ w3p, float* __restrict__ y,
    const unsigned* __restrict__ offsets, const unsigned* __restrict__ counts,
    const unsigned* __restrict__ gtok, const float* __restrict__ ggate) {
  int bx = blockIdx.x;
  int e = bx / (32 * 8); int rem = bx - e * 32 * 8;
  int rb = rem / 8, cb = rem % 8;
  int cnt = (int)counts[e];
  if (rb * 128 >= cnt) return;
  int base = (int)offsets[e];

  __shared__ unsigned short As[128 * 64];
  __shared__ unsigned short Bs[128 * 64];

  int tid = threadIdx.x, wave = tid >> 6, lane = tid & 63;
  int wm = wave >> 2, wn = wave & 3;
  int qr = lane >> 3;
  int qc = (lane & 7) * 8;
  int sr = tid >> 3;
  int sc = (tid & 7) * 8;

  f32x4 acc[4][2] = {};

  const unsigned short* a_src = h + (size_t)(base + rb * 128) * FD;
  size_t wofs = ((size_t)e * CD + cb * 128) * FD;
  const unsigned short* b_bf = (const unsigned short*)w3p + wofs;
  const float* b_f = (const float*)w3p + wofs;

  for (int kt = 0; kt < FD / 64; ++kt) {
    int k0 = kt * 64;
    __syncthreads();
    if (WB) {
#pragma unroll
      for (int it = 0; it < 2; ++it) {
        int q = wave + it * 8;
        int row = q * 8 + qr;
        gld16(&As[q * 512], a_src + (size_t)row * FD + k0 + qc);
        gld16(&Bs[q * 512], b_bf  + (size_t)row * FD + k0 + qc);
      }
    } else {
#pragma unroll
      for (int it = 0; it < 2; ++it) {
        int r = sr + it * 64;
        *(u16x8*)&As[r * 64 + sc] = *(const u16x8*)(a_src + (size_t)r * FD + k0 + sc);
        const float4* s1 = (const float4*)(b_f + (size_t)r * FD + k0 + sc);
        float4 fa = s1[0], fb = s1[1];
        *(u16x8*)&Bs[r * 64 + sc] = u16x8{f2bf(fa.x), f2bf(fa.y), f2bf(fa.z), f2bf(fa.w),
                                          f2bf(fb.x), f2bf(fb.y), f2bf(fb.z), f2bf(fb.w)};
      }
    }
    __syncthreads();
#pragma unroll
    for (int kk = 0; kk < 2; ++kk) {
      int ko = kk * 32 + (lane >> 4) * 8;
      bf16x8 af[4];
#pragma unroll
      for (int mi = 0; mi < 4; ++mi)
        af[mi] = *(const bf16x8*)&As[(wm * 64 + mi * 16 + (lane & 15)) * 64 + ko];
#pragma unroll
      for (int ni = 0; ni < 2; ++ni) {
        int brow = wn * 32 + ni * 16 + (lane & 15);
        bf16x8 bfr = *(const bf16x8*)&Bs[brow * 64 + ko];
#pragma unroll
        for (int mi = 0; mi < 4; ++mi)
          acc[mi][ni] = MFMA16(af[mi], bfr, acc[mi][ni]);
      }
    }
  }
#pragma unroll
  for (int mi = 0; mi < 4; ++mi) {
#pragma unroll
    for (int r4 = 0; r4 < 4; ++r4) {
      int rloc = rb * 128 + wm * 64 + mi * 16 + (lane >> 4) * 4 + r4;
      if (rloc < cnt) {
        unsigned t = gtok[base + rloc];
        float g = ggate[base + rloc];
#pragma unroll
        for (int ni = 0; ni < 2; ++ni) {
          int c = cb * 128 + wn * 32 + ni * 16 + (lane & 15);
          atomicAdd(&y[(size_t)t * CD + c], g * acc[mi][ni][r4]);
        }
      }
    }
  }
}

// ---------------- launch ----------------
extern "C" void kernel_launch(void* const* d_in, const int* in_sizes, int n_in,
                              void* d_out, int out_size, void* d_ws, size_t ws_size,
                              hipStream_t stream) {
  const float* x  = (const float*)d_in[0];
  const float* rw = (const float*)d_in[1];
  const float* w1 = (const float*)d_in[2];
  const float* w2 = (const float*)d_in[3];
  const float* w3 = (const float*)d_in[4];
  float* y = (float*)d_out;

  char* ws = (char*)d_ws;
  unsigned* counts  = (unsigned*)(ws + 0);
  unsigned* cursors = (unsigned*)(ws + 32);
  unsigned* offsets = (unsigned*)(ws + 64);
  unsigned* pcnt    = (unsigned*)(ws + 256);                       // RBLK*NE u32 = 8KB
  float*    ppsum   = (float*)(ws + 256 + 4 * RBLK * NE);          // 8KB
  size_t o = 256 + 8 * (size_t)RBLK * NE;
  unsigned* t2e     = (unsigned*)(ws + o);  o += 4 * (size_t)NPAIR;
  float*    t2g     = (float*)(ws + o);     o += 4 * (size_t)NPAIR;
  unsigned* gtok    = (unsigned*)(ws + o);  o += 4 * (size_t)NPAD;
  float*    ggate   = (float*)(ws + o);     o += 4 * (size_t)NPAD;
  o = (o + 511) & ~(size_t)511;
  unsigned short* xg = (unsigned short*)(ws + o);   o += (size_t)NPAD * CD * 2;
  unsigned short* hb = (unsigned short*)(ws + o);   o += (size_t)NPAD * FD * 2;
  unsigned short* w1b = (unsigned short*)(ws + o);  o += (size_t)NE * FD * CD * 2;
  unsigned short* w2b = (unsigned short*)(ws + o);  o += (size_t)NE * FD * CD * 2;
  unsigned short* w3b = (unsigned short*)(ws + o);  o += (size_t)NE * CD * FD * 2;
  size_t full_need = o;
  bool full = ws_size >= full_need;

  hipMemsetAsync(d_out, 0, (size_t)NTOK * CD * sizeof(float), stream);
  hipMemsetAsync(ws, 0, 96, stream);   // counts, cursors, offsets

  router_kernel<<<RBLK, 256, 0, stream>>>(x, rw, pcnt, ppsum, t2e, t2g);
  scan_kernel<<<1, 64, 0, stream>>>(pcnt, ppsum, counts, offsets, y + (size_t)NTOK * CD);
  build_kernel<<<NPAIR / 256, 256, 0, stream>>>(t2e, t2g, offsets, cursors, gtok, ggate);
  gather_kernel<<<NPAIR / 4, 256, 0, stream>>>(x, gtok, xg);

  if (full) {
    int n8 = NE * FD * CD / 8;
    convert3_kernel<<<3 * 2048, 256, 0, stream>>>((const float4*)w1, (u16x8*)w1b,
                                                  (const float4*)w2, (u16x8*)w2b,
                                                  (const float4*)w3, (u16x8*)w3b, n8);
    gemm1_kernel<true><<<NE * 32 * 28, 512, 0, stream>>>(xg, w1b, w2b, hb, offsets, counts);
    gemm2_kernel<true><<<NE * 32 * 8, 512, 0, stream>>>(hb, w3b, y, offsets, counts, gtok, ggate);
  } else {
    gemm1_kernel<false><<<NE * 32 * 28, 512, 0, stream>>>(xg, w1, w2, hb, offsets, counts);
    gemm2_kernel<false><<<NE * 32 * 8, 512, 0, stream>>>(hb, w3, y, offsets, counts, gtok, ggate);
  }
}

// Round 6
// 752.465 us; speedup vs baseline: 1.8284x; 1.1684x over previous
//
#include <hip/hip_runtime.h>

#define NE 8
#define NTOK 4096
#define CD 1024
#define FD 3584
#define NPAIR 8192
#define NPAD 9216   // NPAIR + 8*128 for per-expert 128-row padding
#define RBLK 256    // router blocks
#define RTOK 16     // tokens per router block

typedef __attribute__((ext_vector_type(8))) short bf16x8;
typedef __attribute__((ext_vector_type(4))) float f32x4;
typedef __attribute__((ext_vector_type(8))) unsigned short u16x8;
typedef unsigned int u32;

__device__ __forceinline__ unsigned short f2bf(float f) {
  union { float f; unsigned u; } v; v.f = f;
  unsigned r = v.u + 0x7fffu + ((v.u >> 16) & 1u);
  return (unsigned short)(r >> 16);
}

// async global->LDS, 16B per lane; lds base must be wave-uniform (HW: base + lane*16)
__device__ __forceinline__ void gld16(unsigned short* lds, const unsigned short* g) {
  __builtin_amdgcn_global_load_lds(
      (const __attribute__((address_space(1))) u32*)g,
      (__attribute__((address_space(3))) u32*)lds, 16, 0, 0);
}

#define MFMA16(a, b, c) __builtin_amdgcn_mfma_f32_16x16x32_bf16((a), (b), (c), 0, 0, 0)

// Swizzle convention (full path only): a buffer row r stores LOGICAL 16B-chunk j at
// PHYSICAL chunk (j & ~7) | ((j ^ r) & 7)  [XOR involution within each 128B group].
// global_load_lds stages physical chunks linearly; fragment reads XOR elem-col with
// ((row&7)<<3) to recover logical data. Requires tile row-bases to be 8-row aligned
// (expert offsets padded to 128 rows; weight tile bases are multiples of 128).

// ---------------- router: logits, softmax, top-2, gates; block-partial counts/p_sum ----------------
__global__ __launch_bounds__(256) void router_kernel(
    const float* __restrict__ x, const float* __restrict__ rw,
    unsigned* __restrict__ pcnt, float* __restrict__ ppsum,
    unsigned* __restrict__ t2e, float* __restrict__ t2g) {
  __shared__ unsigned s_cnt[NE];
  __shared__ float s_ps[NE];
  if (threadIdx.x < NE) { s_cnt[threadIdx.x] = 0u; s_ps[threadIdx.x] = 0.f; }
  __syncthreads();
  int wave = threadIdx.x >> 6, lane = threadIdx.x & 63;
  float4 w[NE][4];
#pragma unroll
  for (int e = 0; e < NE; ++e) {
    const float4* wr = (const float4*)(rw + (size_t)e * CD);
    w[e][0] = wr[2*lane]; w[e][1] = wr[2*lane+1];
    w[e][2] = wr[128+2*lane]; w[e][3] = wr[129+2*lane];
  }
  for (int it = 0; it < RTOK / 4; ++it) {
    int t = blockIdx.x * RTOK + it * 4 + wave;
    const float4* xr = (const float4*)(x + (size_t)t * CD);
    float4 a0 = xr[2*lane], a1 = xr[2*lane+1], a2 = xr[128+2*lane], a3 = xr[129+2*lane];
    float lg[NE];
#pragma unroll
    for (int e = 0; e < NE; ++e) {
      float s;
      s  = a0.x*w[e][0].x + a0.y*w[e][0].y + a0.z*w[e][0].z + a0.w*w[e][0].w;
      s += a1.x*w[e][1].x + a1.y*w[e][1].y + a1.z*w[e][1].z + a1.w*w[e][1].w;
      s += a2.x*w[e][2].x + a2.y*w[e][2].y + a2.z*w[e][2].z + a2.w*w[e][2].w;
      s += a3.x*w[e][3].x + a3.y*w[e][3].y + a3.z*w[e][3].z + a3.w*w[e][3].w;
      lg[e] = s;
    }
#pragma unroll
    for (int e = 0; e < NE; ++e)
#pragma unroll
      for (int off = 32; off; off >>= 1) lg[e] += __shfl_xor(lg[e], off);
    if (lane == 0) {
      float m = lg[0];
#pragma unroll
      for (int e = 1; e < NE; ++e) m = fmaxf(m, lg[e]);
      float p[NE], s = 0.f;
#pragma unroll
      for (int e = 0; e < NE; ++e) { p[e] = expf(lg[e] - m); s += p[e]; }
      float inv = 1.f / s;
      int i1 = 0; float b1 = p[0];
#pragma unroll
      for (int e = 1; e < NE; ++e) if (p[e] > b1) { b1 = p[e]; i1 = e; }
      int i2 = -1; float b2 = -1.f;
#pragma unroll
      for (int e = 0; e < NE; ++e) if (e != i1 && p[e] > b2) { b2 = p[e]; i2 = e; }
      float gs = 1.f / (b1 + b2);
      t2e[2*t]   = (unsigned)i1; t2g[2*t]   = b1 * gs;
      t2e[2*t+1] = (unsigned)i2; t2g[2*t+1] = b2 * gs;
      atomicAdd(&s_cnt[i1], 1u);
      atomicAdd(&s_cnt[i2], 1u);
#pragma unroll
      for (int e = 0; e < NE; ++e) atomicAdd(&s_ps[e], p[e] * inv);
    }
  }
  __syncthreads();
  if (threadIdx.x < NE) {
    pcnt[blockIdx.x * NE + threadIdx.x]  = s_cnt[threadIdx.x];
    ppsum[blockIdx.x * NE + threadIdx.x] = s_ps[threadIdx.x];
  }
}

// ---------------- scan: reduce partials -> counts, 128-padded offsets, aux ----------------
__global__ void scan_kernel(const unsigned* __restrict__ pcnt, const float* __restrict__ ppsum,
                            unsigned* __restrict__ counts, unsigned* __restrict__ offsets,
                            float* __restrict__ aux_out) {
  int lane = threadIdx.x & 63;
  int e = lane >> 3, c = lane & 7;
  unsigned cs = 0; float ps = 0.f;
  for (int b = c; b < RBLK; b += 8) { cs += pcnt[b * NE + e]; ps += ppsum[b * NE + e]; }
#pragma unroll
  for (int off = 1; off < 8; off <<= 1) {
    cs += __shfl_xor(cs, off);
    ps += __shfl_xor(ps, off);
  }
  __shared__ unsigned tc[NE];
  __shared__ float tp[NE];
  if (c == 0) { tc[e] = cs; tp[e] = ps; }
  __syncthreads();
  if (threadIdx.x == 0) {
    unsigned off = 0; float aux = 0.f;
    for (int i = 0; i < NE; ++i) {
      counts[i] = tc[i]; offsets[i] = off;
      off = (off + tc[i] + 127u) & ~127u;   // 128-row pad: keeps tile bases 8-row aligned
      aux += ((float)tc[i] / (float)NPAIR) * (tp[i] / (float)NTOK);
    }
    *aux_out = (float)NE * aux;
  }
}

// ---------------- build: block-ranked compaction; ipos inverse map; 8 atomics/block ----------------
__global__ __launch_bounds__(256) void build_kernel(
    const unsigned* __restrict__ t2e, const float* __restrict__ t2g,
    const unsigned* __restrict__ offsets, unsigned* __restrict__ cursors,
    unsigned* __restrict__ ipos, float* __restrict__ ggate) {
  __shared__ unsigned cnt_l[NE], base_l[NE];
  if (threadIdx.x < NE) cnt_l[threadIdx.x] = 0u;
  __syncthreads();
  int p = blockIdx.x * 256 + threadIdx.x;
  unsigned e = t2e[p];
  unsigned r = atomicAdd(&cnt_l[e], 1u);
  __syncthreads();
  if (threadIdx.x < NE)
    base_l[threadIdx.x] = offsets[threadIdx.x] + atomicAdd(&cursors[threadIdx.x], cnt_l[threadIdx.x]);
  __syncthreads();
  unsigned g = base_l[e] + r;
  ipos[p] = g;
  ggate[g] = t2g[p];
}

// ---------------- gather: x[token] -> xg[group row], fp32->bf16, optional pre-swizzle ----------------
template<bool SW>
__global__ __launch_bounds__(256) void gather_kernel(
    const float* __restrict__ x, const unsigned* __restrict__ ipos,
    unsigned short* __restrict__ xg) {
  int wave = threadIdx.x >> 6, lane = threadIdx.x & 63;
  int p = blockIdx.x * 4 + wave;          // pair index; covers every valid group row once
  unsigned g = ipos[p];
  int t = p >> 1;
  const float4* xr = (const float4*)(x + (size_t)t * CD);
  unsigned short* dst = xg + (size_t)g * CD;
#pragma unroll
  for (int j = 0; j < 2; ++j) {
    float4 a = xr[j*128 + 2*lane], b = xr[j*128 + 2*lane + 1];
    int ch = j * 64 + lane;
    int chp = SW ? ((ch & ~7) | ((ch ^ (int)g) & 7)) : ch;
    *(u16x8*)(dst + chp * 8) =
        u16x8{f2bf(a.x), f2bf(a.y), f2bf(a.z), f2bf(a.w), f2bf(b.x), f2bf(b.y), f2bf(b.z), f2bf(b.w)};
  }
}

// ---------------- weight fp32 -> bf16 convert, pre-swizzled layout, 3 segments ----------------
__global__ __launch_bounds__(256) void convert3_kernel(
    const float4* __restrict__ s1, u16x8* __restrict__ d1,
    const float4* __restrict__ s2, u16x8* __restrict__ d2,
    const float4* __restrict__ s3, u16x8* __restrict__ d3, int n8each) {
  int G = gridDim.x / 3;
  int seg = blockIdx.x / G;
  int bid = blockIdx.x - seg * G;
  const float4* src = seg == 0 ? s1 : (seg == 1 ? s2 : s3);
  u16x8*       dst = seg == 0 ? d1 : (seg == 1 ? d2 : d3);
  int cpr = (seg == 2) ? (FD / 8) : (CD / 8);   // chunks per row: w3=448, w1/w2=128
  int i = bid * 256 + threadIdx.x;
  int stride = G * 256;
  for (; i < n8each; i += stride) {
    float4 a = src[2*i], b = src[2*i+1];
    int r = i / cpr;
    int j = i - r * cpr;
    int jp = (j & ~7) | ((j ^ r) & 7);
    dst[(size_t)r * cpr + jp] =
        u16x8{f2bf(a.x), f2bf(a.y), f2bf(a.z), f2bf(a.w), f2bf(b.x), f2bf(b.y), f2bf(b.z), f2bf(b.w)};
  }
}

// ---------------- GEMM1: h = (x@w1^T) * silu(x@w2^T), grouped by expert ----------------
// Full path: 128x128 tile, BK=64, LDS double-buffer, prefetch-before-compute,
// ONE barrier/K-step, swizzled fragment reads (conflict-free).
template<bool WB>
__global__ __launch_bounds__(512, 2) void gemm1_kernel(
    const unsigned short* __restrict__ xg, const void* __restrict__ w1p, const void* __restrict__ w2p,
    unsigned short* __restrict__ h, const unsigned* __restrict__ offsets, const unsigned* __restrict__ counts) {
  int bx = blockIdx.x;
  int e = bx / (32 * 28); int rem = bx - e * 32 * 28;
  int rb = rem / 28, cb = rem % 28;
  int cnt = (int)counts[e];
  if (rb * 128 >= cnt) return;
  int base = (int)offsets[e];

  __shared__ unsigned short As[2][128 * 64];   // 96 KB total with dbuf (full path)
  __shared__ unsigned short B1s[2][128 * 64];
  __shared__ unsigned short B2s[2][128 * 64];

  int tid = threadIdx.x, wave = tid >> 6, lane = tid & 63;
  int wm = wave >> 2, wn = wave & 3;
  int ln15 = lane & 15;
  int qr = lane >> 3;            // staging: row within 8-row chunk
  int qc = (lane & 7) * 8;       // staging: col elems
  int sr = tid >> 3;             // lean staging row 0..63
  int sc = (tid & 7) * 8;
  int sw = WB ? ((lane & 7) << 3) : 0;    // fragment-read swizzle (rows&7 == lane&7)

  f32x4 acc1[4][2] = {};
  f32x4 acc2[4][2] = {};

  const unsigned short* a_src = xg + (size_t)(base + rb * 128) * CD;
  size_t wofs = ((size_t)e * FD + cb * 128) * CD;
  const unsigned short* b1_bf = (const unsigned short*)w1p + wofs;
  const unsigned short* b2_bf = (const unsigned short*)w2p + wofs;
  const float* b1_f = (const float*)w1p + wofs;
  const float* b2_f = (const float*)w2p + wofs;

  if (WB) {
    // ---- prefetch-dbuf pipeline ----
    auto stage = [&](int buf, int k0) {
#pragma unroll
      for (int it = 0; it < 2; ++it) {
        int q = wave + it * 8;
        int row = q * 8 + qr;
        gld16(&As[buf][q * 512],  a_src + (size_t)row * CD + k0 + qc);
        gld16(&B1s[buf][q * 512], b1_bf + (size_t)row * CD + k0 + qc);
        gld16(&B2s[buf][q * 512], b2_bf + (size_t)row * CD + k0 + qc);
      }
    };
    stage(0, 0);
    __syncthreads();
    int cur = 0;
    for (int kt = 0; kt < CD / 64; ++kt) {
      if (kt + 1 < CD / 64) stage(cur ^ 1, (kt + 1) * 64);   // issue BEFORE compute
      const unsigned short* Ab = As[cur];
      const unsigned short* B1b = B1s[cur];
      const unsigned short* B2b = B2s[cur];
#pragma unroll
      for (int kk = 0; kk < 2; ++kk) {
        int ko = kk * 32 + (lane >> 4) * 8;
        int koS = ko ^ sw;
        bf16x8 af[4];
#pragma unroll
        for (int mi = 0; mi < 4; ++mi)
          af[mi] = *(const bf16x8*)&Ab[(wm * 64 + mi * 16 + ln15) * 64 + koS];
#pragma unroll
        for (int ni = 0; ni < 2; ++ni) {
          int brow = wn * 32 + ni * 16 + ln15;
          bf16x8 b1 = *(const bf16x8*)&B1b[brow * 64 + koS];
          bf16x8 b2 = *(const bf16x8*)&B2b[brow * 64 + koS];
#pragma unroll
          for (int mi = 0; mi < 4; ++mi) {
            acc1[mi][ni] = MFMA16(af[mi], b1, acc1[mi][ni]);
            acc2[mi][ni] = MFMA16(af[mi], b2, acc2[mi][ni]);
          }
        }
      }
      __syncthreads();   // drains vmcnt (stage of cur^1) + lgkm (our reads of cur)
      cur ^= 1;
    }
  } else {
    // ---- lean fallback: single-buffer 2-barrier, fp32 weights converted in-flight ----
    for (int kt = 0; kt < CD / 64; ++kt) {
      int k0 = kt * 64;
      __syncthreads();
#pragma unroll
      for (int it = 0; it < 2; ++it) {
        int r = sr + it * 64;
        *(u16x8*)&As[0][r * 64 + sc] = *(const u16x8*)(a_src + (size_t)r * CD + k0 + sc);
        const float4* s1 = (const float4*)(b1_f + (size_t)r * CD + k0 + sc);
        float4 fa = s1[0], fb = s1[1];
        *(u16x8*)&B1s[0][r * 64 + sc] = u16x8{f2bf(fa.x), f2bf(fa.y), f2bf(fa.z), f2bf(fa.w),
                                              f2bf(fb.x), f2bf(fb.y), f2bf(fb.z), f2bf(fb.w)};
        const float4* s2 = (const float4*)(b2_f + (size_t)r * CD + k0 + sc);
        float4 ga = s2[0], gb = s2[1];
        *(u16x8*)&B2s[0][r * 64 + sc] = u16x8{f2bf(ga.x), f2bf(ga.y), f2bf(ga.z), f2bf(ga.w),
                                              f2bf(gb.x), f2bf(gb.y), f2bf(gb.z), f2bf(gb.w)};
      }
      __syncthreads();
#pragma unroll
      for (int kk = 0; kk < 2; ++kk) {
        int ko = kk * 32 + (lane >> 4) * 8;
        bf16x8 af[4];
#pragma unroll
        for (int mi = 0; mi < 4; ++mi)
          af[mi] = *(const bf16x8*)&As[0][(wm * 64 + mi * 16 + ln15) * 64 + ko];
#pragma unroll
        for (int ni = 0; ni < 2; ++ni) {
          int brow = wn * 32 + ni * 16 + ln15;
          bf16x8 b1 = *(const bf16x8*)&B1s[0][brow * 64 + ko];
          bf16x8 b2 = *(const bf16x8*)&B2s[0][brow * 64 + ko];
#pragma unroll
          for (int mi = 0; mi < 4; ++mi) {
            acc1[mi][ni] = MFMA16(af[mi], b1, acc1[mi][ni]);
            acc2[mi][ni] = MFMA16(af[mi], b2, acc2[mi][ni]);
          }
        }
      }
    }
  }
  // epilogue: h = (x.w1) * silu(x.w2); store pre-swizzled (WB) so gemm2 staging matches
#pragma unroll
  for (int mi = 0; mi < 4; ++mi) {
#pragma unroll
    for (int ni = 0; ni < 2; ++ni) {
      int c = cb * 128 + wn * 32 + ni * 16 + ln15;
#pragma unroll
      for (int r4 = 0; r4 < 4; ++r4) {
        int r = rb * 128 + wm * 64 + mi * 16 + (lane >> 4) * 4 + r4;
        if (r < cnt) {
          float z = acc2[mi][ni][r4];
          float sig = 1.f / (1.f + expf(-z));
          float v = acc1[mi][ni][r4] * (z * sig);
          int cc = WB ? (c ^ ((r & 7) << 3)) : c;
          h[(size_t)(base + r) * FD + cc] = f2bf(v);
        }
      }
    }
  }
}

// ---------------- GEMM2: yp[g] = gate * (h @ w3^T)  (plain stores; no atomics) ----------------
template<bool WB>
__global__ __launch_bounds__(512, 2) void gemm2_kernel(
    const unsigned short* __restrict__ h, const void* __restrict__ w3p, float* __restrict__ yp,
    const unsigned* __restrict__ offsets, const unsigned* __restrict__ counts,
    const float* __restrict__ ggate) {
  int bx = blockIdx.x;
  int e = bx / (32 * 8); int rem = bx - e * 32 * 8;
  int rb = rem / 8, cb = rem % 8;
  int cnt = (int)counts[e];
  if (rb * 128 >= cnt) return;
  int base = (int)offsets[e];

  __shared__ unsigned short As[2][128 * 64];   // 64 KB with dbuf
  __shared__ unsigned short Bs[2][128 * 64];

  int tid = threadIdx.x, wave = tid >> 6, lane = tid & 63;
  int wm = wave >> 2, wn = wave & 3;
  int ln15 = lane & 15;
  int qr = lane >> 3;
  int qc = (lane & 7) * 8;
  int sr = tid >> 3;
  int sc = (tid & 7) * 8;
  int sw = WB ? ((lane & 7) << 3) : 0;

  f32x4 acc[4][2] = {};

  const unsigned short* a_src = h + (size_t)(base + rb * 128) * FD;
  size_t wofs = ((size_t)e * CD + cb * 128) * FD;
  const unsigned short* b_bf = (const unsigned short*)w3p + wofs;
  const float* b_f = (const float*)w3p + wofs;

  if (WB) {
    auto stage = [&](int buf, int k0) {
#pragma unroll
      for (int it = 0; it < 2; ++it) {
        int q = wave + it * 8;
        int row = q * 8 + qr;
        gld16(&As[buf][q * 512], a_src + (size_t)row * FD + k0 + qc);
        gld16(&Bs[buf][q * 512], b_bf  + (size_t)row * FD + k0 + qc);
      }
    };
    stage(0, 0);
    __syncthreads();
    int cur = 0;
    for (int kt = 0; kt < FD / 64; ++kt) {
      if (kt + 1 < FD / 64) stage(cur ^ 1, (kt + 1) * 64);
      const unsigned short* Ab = As[cur];
      const unsigned short* Bb = Bs[cur];
#pragma unroll
      for (int kk = 0; kk < 2; ++kk) {
        int ko = kk * 32 + (lane >> 4) * 8;
        int koS = ko ^ sw;
        bf16x8 af[4];
#pragma unroll
        for (int mi = 0; mi < 4; ++mi)
          af[mi] = *(const bf16x8*)&Ab[(wm * 64 + mi * 16 + ln15) * 64 + koS];
#pragma unroll
        for (int ni = 0; ni < 2; ++ni) {
          int brow = wn * 32 + ni * 16 + ln15;
          bf16x8 bfr = *(const bf16x8*)&Bb[brow * 64 + koS];
#pragma unroll
          for (int mi = 0; mi < 4; ++mi)
            acc[mi][ni] = MFMA16(af[mi], bfr, acc[mi][ni]);
        }
      }
      __syncthreads();
      cur ^= 1;
    }
  } else {
    for (int kt = 0; kt < FD / 64; ++kt) {
      int k0 = kt * 64;
      __syncthreads();
#pragma unroll
      for (int it = 0; it < 2; ++it) {
        int r = sr + it * 64;
        *(u16x8*)&As[0][r * 64 + sc] = *(const u16x8*)(a_src + (size_t)r * FD + k0 + sc);
        const float4* s1 = (const float4*)(b_f + (size_t)r * FD + k0 + sc);
        float4 fa = s1[0], fb = s1[1];
        *(u16x8*)&Bs[0][r * 64 + sc] = u16x8{f2bf(fa.x), f2bf(fa.y), f2bf(fa.z), f2bf(fa.w),
                                             f2bf(fb.x), f2bf(fb.y), f2bf(fb.z), f2bf(fb.w)};
      }
      __syncthreads();
#pragma unroll
      for (int kk = 0; kk < 2; ++kk) {
        int ko = kk * 32 + (lane >> 4) * 8;
        bf16x8 af[4];
#pragma unroll
        for (int mi = 0; mi < 4; ++mi)
          af[mi] = *(const bf16x8*)&As[0][(wm * 64 + mi * 16 + ln15) * 64 + ko];
#pragma unroll
        for (int ni = 0; ni < 2; ++ni) {
          int brow = wn * 32 + ni * 16 + ln15;
          bf16x8 bfr = *(const bf16x8*)&Bs[0][brow * 64 + ko];
#pragma unroll
          for (int mi = 0; mi < 4; ++mi)
            acc[mi][ni] = MFMA16(af[mi], bfr, acc[mi][ni]);
        }
      }
    }
  }
  // epilogue: gated plain stores to per-pair rows (linear layout)
#pragma unroll
  for (int mi = 0; mi < 4; ++mi) {
#pragma unroll
    for (int r4 = 0; r4 < 4; ++r4) {
      int rloc = rb * 128 + wm * 64 + mi * 16 + (lane >> 4) * 4 + r4;
      if (rloc < cnt) {
        float g = ggate[base + rloc];
#pragma unroll
        for (int ni = 0; ni < 2; ++ni) {
          int c = cb * 128 + wn * 32 + ni * 16 + ln15;
          yp[(size_t)(base + rloc) * CD + c] = g * acc[mi][ni][r4];
        }
      }
    }
  }
}

// ---------------- combine: y[t] = yp[ipos[2t]] + yp[ipos[2t+1]] ----------------
__global__ __launch_bounds__(256) void combine_kernel(
    const float* __restrict__ yp, const unsigned* __restrict__ ipos, float* __restrict__ y) {
  int wave = threadIdx.x >> 6, lane = threadIdx.x & 63;
  int t = blockIdx.x * 4 + wave;
  unsigned g0 = ipos[2*t], g1 = ipos[2*t+1];
  const float4* r0 = (const float4*)(yp + (size_t)g0 * CD);
  const float4* r1 = (const float4*)(yp + (size_t)g1 * CD);
  float4* yo = (float4*)(y + (size_t)t * CD);
#pragma unroll
  for (int j = 0; j < 4; ++j) {
    float4 a = r0[j*64 + lane], b = r1[j*64 + lane];
    yo[j*64 + lane] = float4{a.x + b.x, a.y + b.y, a.z + b.z, a.w + b.w};
  }
}

// ---------------- launch ----------------
extern "C" void kernel_launch(void* const* d_in, const int* in_sizes, int n_in,
                              void* d_out, int out_size, void* d_ws, size_t ws_size,
                              hipStream_t stream) {
  const float* x  = (const float*)d_in[0];
  const float* rw = (const float*)d_in[1];
  const float* w1 = (const float*)d_in[2];
  const float* w2 = (const float*)d_in[3];
  const float* w3 = (const float*)d_in[4];
  float* y = (float*)d_out;

  char* ws = (char*)d_ws;
  unsigned* counts  = (unsigned*)(ws + 0);
  unsigned* cursors = (unsigned*)(ws + 32);
  unsigned* offsets = (unsigned*)(ws + 64);
  unsigned* pcnt    = (unsigned*)(ws + 256);
  float*    ppsum   = (float*)(ws + 256 + 4 * RBLK * NE);
  size_t o = 256 + 8 * (size_t)RBLK * NE;
  unsigned* t2e     = (unsigned*)(ws + o);  o += 4 * (size_t)NPAIR;
  float*    t2g     = (float*)(ws + o);     o += 4 * (size_t)NPAIR;
  unsigned* ipos    = (unsigned*)(ws + o);  o += 4 * (size_t)NPAIR;
  float*    ggate   = (float*)(ws + o);     o += 4 * (size_t)NPAD;
  o = (o + 511) & ~(size_t)511;
  unsigned short* xg = (unsigned short*)(ws + o);   o += (size_t)NPAD * CD * 2;
  unsigned short* hb = (unsigned short*)(ws + o);   o += (size_t)NPAD * FD * 2;
  size_t lean_o = o;
  unsigned short* w1b = (unsigned short*)(ws + o);  o += (size_t)NE * FD * CD * 2;
  unsigned short* w2b = (unsigned short*)(ws + o);  o += (size_t)NE * FD * CD * 2;
  unsigned short* w3b = (unsigned short*)(ws + o);  o += (size_t)NE * CD * FD * 2;
  size_t full_need = o;                                    // ~262 MB (yp aliases w1b)
  size_t lean_need = lean_o + (size_t)NPAD * CD * 4;       // ~123 MB
  bool full = ws_size >= full_need;
  float* yp = full ? (float*)w1b                            // w1b dead after gemm1
                   : (float*)(ws + lean_o);
  (void)lean_need;

  hipMemsetAsync(ws, 0, 96, stream);   // counts, cursors (offsets overwritten by scan)

  router_kernel<<<RBLK, 256, 0, stream>>>(x, rw, pcnt, ppsum, t2e, t2g);
  scan_kernel<<<1, 64, 0, stream>>>(pcnt, ppsum, counts, offsets, y + (size_t)NTOK * CD);
  build_kernel<<<NPAIR / 256, 256, 0, stream>>>(t2e, t2g, offsets, cursors, ipos, ggate);

  if (full) {
    gather_kernel<true><<<NPAIR / 4, 256, 0, stream>>>(x, ipos, xg);
    int n8 = NE * FD * CD / 8;
    convert3_kernel<<<3 * 2048, 256, 0, stream>>>((const float4*)w1, (u16x8*)w1b,
                                                  (const float4*)w2, (u16x8*)w2b,
                                                  (const float4*)w3, (u16x8*)w3b, n8);
    gemm1_kernel<true><<<NE * 32 * 28, 512, 0, stream>>>(xg, w1b, w2b, hb, offsets, counts);
    gemm2_kernel<true><<<NE * 32 * 8, 512, 0, stream>>>(hb, w3b, yp, offsets, counts, ggate);
  } else {
    gather_kernel<false><<<NPAIR / 4, 256, 0, stream>>>(x, ipos, xg);
    gemm1_kernel<false><<<NE * 32 * 28, 512, 0, stream>>>(xg, w1, w2, hb, offsets, counts);
    gemm2_kernel<false><<<NE * 32 * 8, 512, 0, stream>>>(hb, w3, yp, offsets, counts, ggate);
  }
  combine_kernel<<<NTOK / 4, 256, 0, stream>>>(yp, ipos, y);
}